// Round 2
// baseline (18.317 us; speedup 1.0000x reference)
//
#include <hip/hip_runtime.h>
#include <hip/hip_bf16.h>

#define NMOL 64
#define DIM 64
#define MTOT 8192
#define NPROP 452
#define LDSP 80    // LDS row stride in bf16 elems (160B)
#define WPP 456    // Wp_s row stride in bf16 elems (912B)

typedef __attribute__((ext_vector_type(8))) short bf16x8;
typedef __attribute__((ext_vector_type(4))) short bf16x4;
typedef __attribute__((ext_vector_type(4))) float f32x4;

__device__ __forceinline__ unsigned short f2bf(float x) {
  union { float f; unsigned u; } v; v.f = x;
  unsigned r = v.u + 0x7FFFu + ((v.u >> 16) & 1u);   // round-to-nearest-even
  return (unsigned short)(r >> 16);
}
__device__ __forceinline__ float bf2f(unsigned short b) {
  union { unsigned u; float f; } v; v.u = ((unsigned)b) << 16;
  return v.f;
}

__global__ __launch_bounds__(256) void mgnn_kernel(
    const int* __restrict__ fp, const float* __restrict__ adj,
    const float* __restrict__ embed, const float* __restrict__ Wf,
    const float* __restrict__ bfv, const float* __restrict__ Wo,
    const float* __restrict__ bo, const float* __restrict__ Wp,
    const float* __restrict__ bp, float* __restrict__ out)
{
  __shared__ unsigned short A_s[64 * LDSP];        // adjacency block, [i][j]
  __shared__ unsigned short V_s[64 * LDSP];        // v, [i][k]
  __shared__ unsigned short HT_s[64 * LDSP];       // h^T, [d][j]
  __shared__ unsigned short WT_s[3][64 * LDSP];    // Wf^T, [d][k]
  __shared__ unsigned short Wp_s[64 * WPP];        // Wp bf16, [k][p]
  __shared__ float bp_s[NPROP];
  __shared__ float bo_s[192];
  __shared__ float bfv_s[192];
  __shared__ float molp[4][64];
  __shared__ float mol_s[64];

  const int t = threadIdx.x;
  const int b = blockIdx.x;
  const int lane = t & 63;
  const int w = t >> 6;        // wave 0..3 -> owns output row panel [16w,16w+16)
  const int c = lane & 15;
  const int g = lane >> 4;

  // ---- stage adjacency diagonal block + embedded node vectors (f32 -> bf16) ----
  {
    const int row = t >> 2;
    const int cq = (t & 3) << 4;
    const float* arow = adj + (size_t)(b * NMOL + row) * MTOT + (size_t)b * NMOL + cq;
    const int f = fp[b * NMOL + row];
    const float* erow = embed + (size_t)f * DIM + cq;
    float va[16], ve[16];
#pragma unroll
    for (int q = 0; q < 4; ++q) {
      const float4 xa = reinterpret_cast<const float4*>(arow)[q];
      const float4 xe = reinterpret_cast<const float4*>(erow)[q];
      va[4*q+0]=xa.x; va[4*q+1]=xa.y; va[4*q+2]=xa.z; va[4*q+3]=xa.w;
      ve[4*q+0]=xe.x; ve[4*q+1]=xe.y; ve[4*q+2]=xe.z; ve[4*q+3]=xe.w;
    }
    bf16x8 pa0, pa1, pe0, pe1;
#pragma unroll
    for (int i = 0; i < 8; ++i) {
      pa0[i] = (short)f2bf(va[i]);   pa1[i] = (short)f2bf(va[8+i]);
      pe0[i] = (short)f2bf(ve[i]);   pe1[i] = (short)f2bf(ve[8+i]);
    }
    *reinterpret_cast<bf16x8*>(&A_s[row * LDSP + cq])     = pa0;
    *reinterpret_cast<bf16x8*>(&A_s[row * LDSP + cq + 8]) = pa1;
    *reinterpret_cast<bf16x8*>(&V_s[row * LDSP + cq])     = pe0;
    *reinterpret_cast<bf16x8*>(&V_s[row * LDSP + cq + 8]) = pe1;
  }
  // ---- stage Wf[l] transposed: WT_s[l][d][k] = Wf[l][k][d] ----
#pragma unroll
  for (int l = 0; l < 3; ++l) {
    const int k = t >> 2;
    const int dq = (t & 3) << 4;
    const float* wrow = Wf + l * DIM * DIM + k * DIM + dq;
#pragma unroll
    for (int q = 0; q < 4; ++q) {
      const float4 x = reinterpret_cast<const float4*>(wrow)[q];
      WT_s[l][(dq + 4*q + 0) * LDSP + k] = f2bf(x.x);
      WT_s[l][(dq + 4*q + 1) * LDSP + k] = f2bf(x.y);
      WT_s[l][(dq + 4*q + 2) * LDSP + k] = f2bf(x.z);
      WT_s[l][(dq + 4*q + 3) * LDSP + k] = f2bf(x.w);
    }
  }
  // ---- stage head: Wp -> bf16 LDS (overlaps the cold HBM latency above) ----
  for (int i = t; i < (DIM * NPROP) / 4; i += 256) {   // 7232 float4 groups
    const float4 x = reinterpret_cast<const float4*>(Wp)[i];
    const int f = i << 2;
    const int k = f / NPROP;            // compiler magic-div (const 452)
    const int p = f - k * NPROP;
    unsigned short* dst = &Wp_s[k * WPP + p];
    dst[0] = f2bf(x.x); dst[1] = f2bf(x.y); dst[2] = f2bf(x.z); dst[3] = f2bf(x.w);
  }
  for (int i = t; i < NPROP; i += 256) bp_s[i] = bp[i];
  if (t < 192) { bo_s[t] = bo[t]; bfv_s[t] = bfv[t]; }
  __syncthreads();

  f32x4 acc[4];
  const int lrow_off = (w * 16 + c) * LDSP;   // LEFT-operand fragment row base

#pragma unroll 1
  for (int l = 0; l < 3; ++l) {
    // ---- matmul1: acc = v @ Wf[l] + bf[l]  (bias via C-init) ----
#pragma unroll
    for (int tc = 0; tc < 4; ++tc) {
      const float bias = bfv_s[l * DIM + tc * 16 + c];
      acc[tc][0] = bias; acc[tc][1] = bias; acc[tc][2] = bias; acc[tc][3] = bias;
    }
#pragma unroll
    for (int kh = 0; kh < 2; ++kh) {
      const int ko = kh * 32 + g * 8;
      const bf16x8 af = *reinterpret_cast<const bf16x8*>(&V_s[lrow_off + ko]);
#pragma unroll
      for (int tc = 0; tc < 4; ++tc) {
        const bf16x8 bb = *reinterpret_cast<const bf16x8*>(&WT_s[l][(tc * 16 + c) * LDSP + ko]);
        acc[tc] = __builtin_amdgcn_mfma_f32_16x16x32_bf16(af, bb, acc[tc], 0, 0, 0);
      }
    }
    // ---- relu (h stays f32 in acc); write h^T to LDS as bf16 ----
#pragma unroll
    for (int tc = 0; tc < 4; ++tc) {
      bf16x4 hp;
#pragma unroll
      for (int r = 0; r < 4; ++r) {
        const float h = fmaxf(acc[tc][r], 0.0f);
        acc[tc][r] = h;
        hp[r] = (short)f2bf(h);
      }
      // C/D: row = 16w + 4g + r, col = 16tc + c; h^T[col][row], 4 rows contiguous -> b64
      *reinterpret_cast<bf16x4*>(&HT_s[(tc * 16 + c) * LDSP + w * 16 + g * 4]) = hp;
    }
    __syncthreads();
    // ---- matmul2: acc += A @ h  (acc already holds h -> hs = h + A@h) ----
#pragma unroll
    for (int kh = 0; kh < 2; ++kh) {
      const int ko = kh * 32 + g * 8;
      const bf16x8 af = *reinterpret_cast<const bf16x8*>(&A_s[lrow_off + ko]);
#pragma unroll
      for (int tc = 0; tc < 4; ++tc) {
        const bf16x8 bb = *reinterpret_cast<const bf16x8*>(&HT_s[(tc * 16 + c) * LDSP + ko]);
        acc[tc] = __builtin_amdgcn_mfma_f32_16x16x32_bf16(af, bb, acc[tc], 0, 0, 0);
      }
    }
    // ---- row-wise L2 normalize ----
    float ss[4] = {0.f, 0.f, 0.f, 0.f};
#pragma unroll
    for (int tc = 0; tc < 4; ++tc)
#pragma unroll
      for (int r = 0; r < 4; ++r) ss[r] += acc[tc][r] * acc[tc][r];
#pragma unroll
    for (int m = 1; m <= 8; m <<= 1) {
#pragma unroll
      for (int r = 0; r < 4; ++r) ss[r] += __shfl_xor(ss[r], m, 64);
    }
    float inv[4];
#pragma unroll
    for (int r = 0; r < 4; ++r) inv[r] = rsqrtf(fmaxf(ss[r], 1e-24f));
#pragma unroll
    for (int tc = 0; tc < 4; ++tc)
#pragma unroll
      for (int r = 0; r < 4; ++r) acc[tc][r] *= inv[r];

    if (l < 2) {
      // write v' back for next layer's matmul1
#pragma unroll
      for (int tc = 0; tc < 4; ++tc)
#pragma unroll
        for (int r = 0; r < 4; ++r)
          V_s[(w * 16 + g * 4 + r) * LDSP + tc * 16 + c] = f2bf(acc[tc][r]);
      __syncthreads();
    }
  }

  // ---- sum-pool over the molecule's 64 nodes ----
  {
    float cs[4];
#pragma unroll
    for (int tc = 0; tc < 4; ++tc) {
      cs[tc] = acc[tc][0] + acc[tc][1] + acc[tc][2] + acc[tc][3];
      cs[tc] += __shfl_xor(cs[tc], 16, 64);
      cs[tc] += __shfl_xor(cs[tc], 32, 64);
    }
    if (lane < 16) {
#pragma unroll
      for (int tc = 0; tc < 4; ++tc) molp[w][tc * 16 + lane] = cs[tc];
    }
  }
  __syncthreads();
  if (t < 64) mol_s[t] = molp[0][t] + molp[1][t] + molp[2][t] + molp[3][t];
  __syncthreads();

  // ---- MLP head (f32; Wo global with fully-unrolled loop -> all loads in flight) ----
  for (int l = 0; l < 3; ++l) {
    float a = 0.f;
    if (t < 64) {
      a = bo_s[l * DIM + t];
      const float* wl = Wo + l * DIM * DIM + t;
#pragma unroll
      for (int k = 0; k < DIM; ++k) a += mol_s[k] * wl[k * DIM];
      a = fmaxf(a, 0.f);
    }
    __syncthreads();
    if (t < 64) mol_s[t] = a;
    __syncthreads();
  }

  // ---- final projection: 2 props/thread from bf16 Wp in LDS ----
  if (t < NPROP / 2) {
    float a0 = bp_s[2 * t], a1 = bp_s[2 * t + 1];
#pragma unroll
    for (int k = 0; k < DIM; ++k) {
      const float m = mol_s[k];
      const unsigned w2 = *reinterpret_cast<const unsigned*>(&Wp_s[k * WPP + 2 * t]);
      a0 += m * bf2f((unsigned short)(w2 & 0xFFFFu));
      a1 += m * bf2f((unsigned short)(w2 >> 16));
    }
    *reinterpret_cast<float2*>(&out[(size_t)b * NPROP + 2 * t]) = make_float2(a0, a1);
  }
}

extern "C" void kernel_launch(void* const* d_in, const int* in_sizes, int n_in,
                              void* d_out, int out_size, void* d_ws, size_t ws_size,
                              hipStream_t stream) {
  const int*   fp    = (const int*)d_in[0];
  const float* adj   = (const float*)d_in[1];
  // d_in[2] = mol_size (scalar, hardcoded 64)
  const float* embed = (const float*)d_in[3];
  const float* Wf    = (const float*)d_in[4];
  const float* bfv   = (const float*)d_in[5];
  const float* Wo    = (const float*)d_in[6];
  const float* bo    = (const float*)d_in[7];
  const float* Wp    = (const float*)d_in[8];
  const float* bp    = (const float*)d_in[9];
  float* out = (float*)d_out;
  mgnn_kernel<<<128, 256, 0, stream>>>(fp, adj, embed, Wf, bfv, Wo, bo, Wp, bp, out);
}

// Round 3
// 14.589 us; speedup vs baseline: 1.2556x; 1.2556x over previous
//
#include <hip/hip_runtime.h>
#include <hip/hip_bf16.h>

#define NMOL 64
#define DIM 64
#define MTOT 8192
#define NPROP 452
#define LDSP 80    // LDS row stride in bf16 elems (160B)

typedef __attribute__((ext_vector_type(8))) short bf16x8;
typedef __attribute__((ext_vector_type(4))) short bf16x4;
typedef __attribute__((ext_vector_type(4))) float f32x4;

__device__ __forceinline__ unsigned short f2bf(float x) {
  union { float f; unsigned u; } v; v.f = x;
  unsigned r = v.u + 0x7FFFu + ((v.u >> 16) & 1u);   // round-to-nearest-even
  return (unsigned short)(r >> 16);
}

__global__ __launch_bounds__(256) void mgnn_kernel(
    const int* __restrict__ fp, const float* __restrict__ adj,
    const float* __restrict__ embed, const float* __restrict__ Wf,
    const float* __restrict__ bfv, const float* __restrict__ Wo,
    const float* __restrict__ bo, const float* __restrict__ Wp,
    const float* __restrict__ bp, float* __restrict__ out)
{
  __shared__ unsigned short A_s[64 * LDSP];        // adjacency block, [i][j]
  __shared__ unsigned short V_s[64 * LDSP];        // v, [i][k]
  __shared__ unsigned short HT_s[64 * LDSP];       // h^T, [d][j]
  __shared__ unsigned short WT_s[3][64 * LDSP];    // Wf^T, [d][k]
  __shared__ float Wo_s[3 * DIM * DIM];            // head weights, f32 [l][k][d]
  __shared__ float bp_s[NPROP];
  __shared__ float bo_s[192];
  __shared__ float bfv_s[192];
  __shared__ float molp[4][64];
  __shared__ float mol_s[64];

  const int t = threadIdx.x;
  const int b = blockIdx.x;
  const int lane = t & 63;
  const int w = t >> 6;        // wave 0..3 -> owns output row panel [16w,16w+16)
  const int c = lane & 15;
  const int g = lane >> 4;

  // ---- stage adjacency diagonal block + embedded node vectors (f32 -> bf16) ----
  {
    const int row = t >> 2;
    const int cq = (t & 3) << 4;
    const float* arow = adj + (size_t)(b * NMOL + row) * MTOT + (size_t)b * NMOL + cq;
    const int f = fp[b * NMOL + row];
    const float* erow = embed + (size_t)f * DIM + cq;
    float va[16], ve[16];
#pragma unroll
    for (int q = 0; q < 4; ++q) {
      const float4 xa = reinterpret_cast<const float4*>(arow)[q];
      const float4 xe = reinterpret_cast<const float4*>(erow)[q];
      va[4*q+0]=xa.x; va[4*q+1]=xa.y; va[4*q+2]=xa.z; va[4*q+3]=xa.w;
      ve[4*q+0]=xe.x; ve[4*q+1]=xe.y; ve[4*q+2]=xe.z; ve[4*q+3]=xe.w;
    }
    bf16x8 pa0, pa1, pe0, pe1;
#pragma unroll
    for (int i = 0; i < 8; ++i) {
      pa0[i] = (short)f2bf(va[i]);   pa1[i] = (short)f2bf(va[8+i]);
      pe0[i] = (short)f2bf(ve[i]);   pe1[i] = (short)f2bf(ve[8+i]);
    }
    *reinterpret_cast<bf16x8*>(&A_s[row * LDSP + cq])     = pa0;
    *reinterpret_cast<bf16x8*>(&A_s[row * LDSP + cq + 8]) = pa1;
    *reinterpret_cast<bf16x8*>(&V_s[row * LDSP + cq])     = pe0;
    *reinterpret_cast<bf16x8*>(&V_s[row * LDSP + cq + 8]) = pe1;
  }
  // ---- stage Wf[l] transposed: WT_s[l][d][k] = Wf[l][k][d] ----
#pragma unroll
  for (int l = 0; l < 3; ++l) {
    const int k = t >> 2;
    const int dq = (t & 3) << 4;
    const float* wrow = Wf + l * DIM * DIM + k * DIM + dq;
#pragma unroll
    for (int q = 0; q < 4; ++q) {
      const float4 x = reinterpret_cast<const float4*>(wrow)[q];
      WT_s[l][(dq + 4*q + 0) * LDSP + k] = f2bf(x.x);
      WT_s[l][(dq + 4*q + 1) * LDSP + k] = f2bf(x.y);
      WT_s[l][(dq + 4*q + 2) * LDSP + k] = f2bf(x.z);
      WT_s[l][(dq + 4*q + 3) * LDSP + k] = f2bf(x.w);
    }
  }
  // ---- stage head weights Wo (f32, pure vector copy) + biases ----
#pragma unroll
  for (int i = 0; i < 12; ++i) {   // 3*64*64/4 = 3072 float4 / 256 threads
    const int idx = t + i * 256;
    const float4 x = reinterpret_cast<const float4*>(Wo)[idx];
    *reinterpret_cast<float4*>(&Wo_s[idx << 2]) = x;
  }
  for (int i = t; i < NPROP; i += 256) bp_s[i] = bp[i];
  if (t < 192) { bo_s[t] = bo[t]; bfv_s[t] = bfv[t]; }
  __syncthreads();

  f32x4 acc[4];
  const int lrow_off = (w * 16 + c) * LDSP;   // LEFT-operand fragment row base

#pragma unroll 1
  for (int l = 0; l < 3; ++l) {
    // ---- matmul1: acc = v @ Wf[l] + bf[l]  (bias via C-init) ----
#pragma unroll
    for (int tc = 0; tc < 4; ++tc) {
      const float bias = bfv_s[l * DIM + tc * 16 + c];
      acc[tc][0] = bias; acc[tc][1] = bias; acc[tc][2] = bias; acc[tc][3] = bias;
    }
#pragma unroll
    for (int kh = 0; kh < 2; ++kh) {
      const int ko = kh * 32 + g * 8;
      const bf16x8 af = *reinterpret_cast<const bf16x8*>(&V_s[lrow_off + ko]);
#pragma unroll
      for (int tc = 0; tc < 4; ++tc) {
        const bf16x8 bb = *reinterpret_cast<const bf16x8*>(&WT_s[l][(tc * 16 + c) * LDSP + ko]);
        acc[tc] = __builtin_amdgcn_mfma_f32_16x16x32_bf16(af, bb, acc[tc], 0, 0, 0);
      }
    }
    // ---- relu (h stays f32 in acc); write h^T to LDS as bf16 ----
#pragma unroll
    for (int tc = 0; tc < 4; ++tc) {
      bf16x4 hp;
#pragma unroll
      for (int r = 0; r < 4; ++r) {
        const float h = fmaxf(acc[tc][r], 0.0f);
        acc[tc][r] = h;
        hp[r] = (short)f2bf(h);
      }
      // C/D: row = 16w + 4g + r, col = 16tc + c; h^T[col][row], 4 rows contiguous -> b64
      *reinterpret_cast<bf16x4*>(&HT_s[(tc * 16 + c) * LDSP + w * 16 + g * 4]) = hp;
    }
    __syncthreads();
    // ---- matmul2: acc += A @ h  (acc already holds h -> hs = h + A@h) ----
#pragma unroll
    for (int kh = 0; kh < 2; ++kh) {
      const int ko = kh * 32 + g * 8;
      const bf16x8 af = *reinterpret_cast<const bf16x8*>(&A_s[lrow_off + ko]);
#pragma unroll
      for (int tc = 0; tc < 4; ++tc) {
        const bf16x8 bb = *reinterpret_cast<const bf16x8*>(&HT_s[(tc * 16 + c) * LDSP + ko]);
        acc[tc] = __builtin_amdgcn_mfma_f32_16x16x32_bf16(af, bb, acc[tc], 0, 0, 0);
      }
    }
    // ---- row-wise L2 normalize ----
    float ss[4] = {0.f, 0.f, 0.f, 0.f};
#pragma unroll
    for (int tc = 0; tc < 4; ++tc)
#pragma unroll
      for (int r = 0; r < 4; ++r) ss[r] += acc[tc][r] * acc[tc][r];
#pragma unroll
    for (int m = 1; m <= 8; m <<= 1) {
#pragma unroll
      for (int r = 0; r < 4; ++r) ss[r] += __shfl_xor(ss[r], m, 64);
    }
    float inv[4];
#pragma unroll
    for (int r = 0; r < 4; ++r) inv[r] = rsqrtf(fmaxf(ss[r], 1e-24f));
#pragma unroll
    for (int tc = 0; tc < 4; ++tc)
#pragma unroll
      for (int r = 0; r < 4; ++r) acc[tc][r] *= inv[r];

    if (l < 2) {
      // write v' back for next layer's matmul1
#pragma unroll
      for (int tc = 0; tc < 4; ++tc)
#pragma unroll
        for (int r = 0; r < 4; ++r)
          V_s[(w * 16 + g * 4 + r) * LDSP + tc * 16 + c] = f2bf(acc[tc][r]);
      __syncthreads();
    }
  }

  // ---- sum-pool over the molecule's 64 nodes ----
  {
    float cs[4];
#pragma unroll
    for (int tc = 0; tc < 4; ++tc) {
      cs[tc] = acc[tc][0] + acc[tc][1] + acc[tc][2] + acc[tc][3];
      cs[tc] += __shfl_xor(cs[tc], 16, 64);
      cs[tc] += __shfl_xor(cs[tc], 32, 64);
    }
    if (lane < 16) {
#pragma unroll
      for (int tc = 0; tc < 4; ++tc) molp[w][tc * 16 + lane] = cs[tc];
    }
  }
  __syncthreads();
  if (t < 64) mol_s[t] = molp[0][t] + molp[1][t] + molp[2][t] + molp[3][t];
  __syncthreads();

  // ---- MLP head: all 256 threads, k split 4 ways (16-FMA chains), LDS weights ----
  const int hd = t & 63;       // output dim
  const int hp = t >> 6;       // k-partition
#pragma unroll 1
  for (int l = 0; l < 3; ++l) {
    float a = 0.f;
    const float* wl = &Wo_s[l * DIM * DIM + hp * 16 * DIM + hd];
#pragma unroll
    for (int kk = 0; kk < 16; ++kk) a += mol_s[hp * 16 + kk] * wl[kk * DIM];
    molp[hp][hd] = a;
    __syncthreads();
    if (t < 64) {
      const float s = bo_s[l * DIM + t] + molp[0][t] + molp[1][t] + molp[2][t] + molp[3][t];
      mol_s[t] = fmaxf(s, 0.f);
    }
    __syncthreads();
  }

  // ---- final projection: 2 props/thread, Wp from global (L2-hot), deep unroll ----
  if (t < NPROP / 2) {
    float a0 = bp_s[2 * t], a1 = bp_s[2 * t + 1];
    const float* wp = Wp + 2 * t;
#pragma unroll 32
    for (int k = 0; k < DIM; ++k) {
      const float2 w2 = *reinterpret_cast<const float2*>(&wp[k * NPROP]);
      const float m = mol_s[k];
      a0 += m * w2.x;
      a1 += m * w2.y;
    }
    *reinterpret_cast<float2*>(&out[(size_t)b * NPROP + 2 * t]) = make_float2(a0, a1);
  }
}

extern "C" void kernel_launch(void* const* d_in, const int* in_sizes, int n_in,
                              void* d_out, int out_size, void* d_ws, size_t ws_size,
                              hipStream_t stream) {
  const int*   fp    = (const int*)d_in[0];
  const float* adj   = (const float*)d_in[1];
  // d_in[2] = mol_size (scalar, hardcoded 64)
  const float* embed = (const float*)d_in[3];
  const float* Wf    = (const float*)d_in[4];
  const float* bfv   = (const float*)d_in[5];
  const float* Wo    = (const float*)d_in[6];
  const float* bo    = (const float*)d_in[7];
  const float* Wp    = (const float*)d_in[8];
  const float* bp    = (const float*)d_in[9];
  float* out = (float*)d_out;
  mgnn_kernel<<<128, 256, 0, stream>>>(fp, adj, embed, Wf, bfv, Wo, bo, Wp, bp, out);
}

// Round 4
// 14.172 us; speedup vs baseline: 1.2925x; 1.0294x over previous
//
#include <hip/hip_runtime.h>
#include <hip/hip_bf16.h>

#define NMOL 64
#define DIM 64
#define MTOT 8192
#define NPROP 452
#define LDSP 80    // LDS row stride in bf16 elems (160B)

typedef __attribute__((ext_vector_type(8))) short bf16x8;
typedef __attribute__((ext_vector_type(4))) short bf16x4;
typedef __attribute__((ext_vector_type(4))) float f32x4;

__device__ __forceinline__ unsigned short f2bf(float x) {
  __hip_bfloat16 h = __float2bfloat16(x);     // RNE; lowers to v_cvt_pk_bf16_f32 pairs
  unsigned short u;
  __builtin_memcpy(&u, &h, 2);
  return u;
}

__global__ __launch_bounds__(256) void mgnn_kernel(
    const int* __restrict__ fp, const float* __restrict__ adj,
    const float* __restrict__ embed, const float* __restrict__ Wf,
    const float* __restrict__ bfv, const float* __restrict__ Wo,
    const float* __restrict__ bo, const float* __restrict__ Wp,
    const float* __restrict__ bp, float* __restrict__ out)
{
  __shared__ unsigned short A_s[64 * LDSP];        // adjacency block, [i][j]
  __shared__ unsigned short V_s[64 * LDSP];        // v, [i][k]
  __shared__ unsigned short HT_s[64 * LDSP];       // h^T, [d][j]
  __shared__ unsigned short WT_s[3][64 * LDSP];    // Wf^T, [d][k]
  __shared__ float Wo_s[3 * DIM * DIM];            // head weights, f32 [l][k][d]
  __shared__ float bo_s[192];
  __shared__ float bfv_s[192];
  __shared__ float molp[4][64];
  __shared__ float mol_s[64];

  const int t = threadIdx.x;
  const int b = blockIdx.x;
  const int lane = t & 63;
  const int w = t >> 6;        // wave 0..3 -> owns output row panel [16w,16w+16)
  const int c = lane & 15;
  const int g = lane >> 4;

  // ---- early prefetch: tail Wp slice (k=0..31) + bp into registers.
  // These loads overlap the entire GNN phase; used only in the projection tail.
  float2 wpre[32];
  float bp0 = 0.f, bp1 = 0.f;
  const int pp = 2 * t;
  if (t < NPROP / 2) {
    bp0 = bp[pp]; bp1 = bp[pp + 1];
#pragma unroll
    for (int k = 0; k < 32; ++k)
      wpre[k] = *reinterpret_cast<const float2*>(&Wp[k * NPROP + pp]);
  }

  // ---- stage adjacency diagonal block + embedded node vectors (f32 -> bf16) ----
  {
    const int row = t >> 2;
    const int cq = (t & 3) << 4;
    const float* arow = adj + (size_t)(b * NMOL + row) * MTOT + (size_t)b * NMOL + cq;
    const int f = fp[b * NMOL + row];
    const float* erow = embed + (size_t)f * DIM + cq;
    float va[16], ve[16];
#pragma unroll
    for (int q = 0; q < 4; ++q) {
      const float4 xa = reinterpret_cast<const float4*>(arow)[q];
      const float4 xe = reinterpret_cast<const float4*>(erow)[q];
      va[4*q+0]=xa.x; va[4*q+1]=xa.y; va[4*q+2]=xa.z; va[4*q+3]=xa.w;
      ve[4*q+0]=xe.x; ve[4*q+1]=xe.y; ve[4*q+2]=xe.z; ve[4*q+3]=xe.w;
    }
    bf16x8 pa0, pa1, pe0, pe1;
#pragma unroll
    for (int i = 0; i < 8; ++i) {
      pa0[i] = (short)f2bf(va[i]);   pa1[i] = (short)f2bf(va[8+i]);
      pe0[i] = (short)f2bf(ve[i]);   pe1[i] = (short)f2bf(ve[8+i]);
    }
    *reinterpret_cast<bf16x8*>(&A_s[row * LDSP + cq])     = pa0;
    *reinterpret_cast<bf16x8*>(&A_s[row * LDSP + cq + 8]) = pa1;
    *reinterpret_cast<bf16x8*>(&V_s[row * LDSP + cq])     = pe0;
    *reinterpret_cast<bf16x8*>(&V_s[row * LDSP + cq + 8]) = pe1;
  }
  // ---- stage Wf[l] transposed: WT_s[l][d][k] = Wf[l][k][d] ----
#pragma unroll
  for (int l = 0; l < 3; ++l) {
    const int k = t >> 2;
    const int dq = (t & 3) << 4;
    const float* wrow = Wf + l * DIM * DIM + k * DIM + dq;
#pragma unroll
    for (int q = 0; q < 4; ++q) {
      const float4 x = reinterpret_cast<const float4*>(wrow)[q];
      WT_s[l][(dq + 4*q + 0) * LDSP + k] = f2bf(x.x);
      WT_s[l][(dq + 4*q + 1) * LDSP + k] = f2bf(x.y);
      WT_s[l][(dq + 4*q + 2) * LDSP + k] = f2bf(x.z);
      WT_s[l][(dq + 4*q + 3) * LDSP + k] = f2bf(x.w);
    }
  }
  // ---- stage head weights Wo (f32, pure vector copy) + biases ----
#pragma unroll
  for (int i = 0; i < 12; ++i) {   // 3*64*64/4 = 3072 float4 / 256 threads
    const int idx = t + i * 256;
    const float4 x = reinterpret_cast<const float4*>(Wo)[idx];
    *reinterpret_cast<float4*>(&Wo_s[idx << 2]) = x;
  }
  if (t < 192) { bo_s[t] = bo[t]; bfv_s[t] = bfv[t]; }
  __syncthreads();

  f32x4 acc[4];
  const int lrow_off = (w * 16 + c) * LDSP;   // LEFT-operand fragment row base

#pragma unroll 1
  for (int l = 0; l < 3; ++l) {
    // ---- matmul1: acc = v @ Wf[l] + bf[l]  (bias via C-init) ----
    // NOTE: wave w's A-frags read V_s rows [16w,16w+16) which THIS wave wrote
    // last layer (or staged) -> no barrier needed before matmul1 (wave-local dep).
#pragma unroll
    for (int tc = 0; tc < 4; ++tc) {
      const float bias = bfv_s[l * DIM + tc * 16 + c];
      acc[tc][0] = bias; acc[tc][1] = bias; acc[tc][2] = bias; acc[tc][3] = bias;
    }
#pragma unroll
    for (int kh = 0; kh < 2; ++kh) {
      const int ko = kh * 32 + g * 8;
      const bf16x8 af = *reinterpret_cast<const bf16x8*>(&V_s[lrow_off + ko]);
#pragma unroll
      for (int tc = 0; tc < 4; ++tc) {
        const bf16x8 bb = *reinterpret_cast<const bf16x8*>(&WT_s[l][(tc * 16 + c) * LDSP + ko]);
        acc[tc] = __builtin_amdgcn_mfma_f32_16x16x32_bf16(af, bb, acc[tc], 0, 0, 0);
      }
    }
    // ---- relu (h stays f32 in acc); write h^T to LDS as bf16 ----
#pragma unroll
    for (int tc = 0; tc < 4; ++tc) {
      bf16x4 hp;
#pragma unroll
      for (int r = 0; r < 4; ++r) {
        const float h = fmaxf(acc[tc][r], 0.0f);
        acc[tc][r] = h;
        hp[r] = (short)f2bf(h);
      }
      // C/D: row = 16w + 4g + r, col = 16tc + c; h^T[col][row], 4 rows contiguous -> b64
      *reinterpret_cast<bf16x4*>(&HT_s[(tc * 16 + c) * LDSP + w * 16 + g * 4]) = hp;
    }
    __syncthreads();   // HT is consumed cross-wave -> this barrier stays
    // ---- matmul2: acc += A @ h  (acc already holds h -> hs = h + A@h) ----
#pragma unroll
    for (int kh = 0; kh < 2; ++kh) {
      const int ko = kh * 32 + g * 8;
      const bf16x8 af = *reinterpret_cast<const bf16x8*>(&A_s[lrow_off + ko]);
#pragma unroll
      for (int tc = 0; tc < 4; ++tc) {
        const bf16x8 bb = *reinterpret_cast<const bf16x8*>(&HT_s[(tc * 16 + c) * LDSP + ko]);
        acc[tc] = __builtin_amdgcn_mfma_f32_16x16x32_bf16(af, bb, acc[tc], 0, 0, 0);
      }
    }
    // ---- row-wise L2 normalize ----
    float ss[4] = {0.f, 0.f, 0.f, 0.f};
#pragma unroll
    for (int tc = 0; tc < 4; ++tc)
#pragma unroll
      for (int r = 0; r < 4; ++r) ss[r] += acc[tc][r] * acc[tc][r];
#pragma unroll
    for (int m = 1; m <= 8; m <<= 1) {
#pragma unroll
      for (int r = 0; r < 4; ++r) ss[r] += __shfl_xor(ss[r], m, 64);
    }
    float inv[4];
#pragma unroll
    for (int r = 0; r < 4; ++r) inv[r] = rsqrtf(fmaxf(ss[r], 1e-24f));
#pragma unroll
    for (int tc = 0; tc < 4; ++tc)
#pragma unroll
      for (int r = 0; r < 4; ++r) acc[tc][r] *= inv[r];

    if (l < 2) {
      // write v' back for next layer's matmul1 — rows [16w,16w+16) are wave-local,
      // so NO barrier here (lgkmcnt ordering suffices).
#pragma unroll
      for (int tc = 0; tc < 4; ++tc)
#pragma unroll
        for (int r = 0; r < 4; ++r)
          V_s[(w * 16 + g * 4 + r) * LDSP + tc * 16 + c] = f2bf(acc[tc][r]);
    }
  }

  // ---- sum-pool over the molecule's 64 nodes ----
  {
    float cs[4];
#pragma unroll
    for (int tc = 0; tc < 4; ++tc) {
      cs[tc] = acc[tc][0] + acc[tc][1] + acc[tc][2] + acc[tc][3];
      cs[tc] += __shfl_xor(cs[tc], 16, 64);
      cs[tc] += __shfl_xor(cs[tc], 32, 64);
    }
    if (lane < 16) {
#pragma unroll
      for (int tc = 0; tc < 4; ++tc) molp[w][tc * 16 + lane] = cs[tc];
    }
  }
  __syncthreads();
  if (t < 64) mol_s[t] = molp[0][t] + molp[1][t] + molp[2][t] + molp[3][t];
  __syncthreads();

  // ---- MLP head: all 256 threads, k split 4 ways (16-FMA chains), LDS weights ----
  const int hd = t & 63;       // output dim
  const int hk = t >> 6;       // k-partition
#pragma unroll 1
  for (int l = 0; l < 3; ++l) {
    float a = 0.f;
    const float* wl = &Wo_s[l * DIM * DIM + hk * 16 * DIM + hd];
#pragma unroll
    for (int kk = 0; kk < 16; ++kk) a += mol_s[hk * 16 + kk] * wl[kk * DIM];
    molp[hk][hd] = a;
    __syncthreads();
    if (t < 64) {
      const float s = bo_s[l * DIM + t] + molp[0][t] + molp[1][t] + molp[2][t] + molp[3][t];
      mol_s[t] = fmaxf(s, 0.f);
    }
    __syncthreads();
  }

  // ---- final projection: 2 props/thread; k<32 from register prefetch, rest global ----
  if (t < NPROP / 2) {
    float a0 = bp0, a1 = bp1;
#pragma unroll
    for (int k = 0; k < 32; ++k) {
      const float m = mol_s[k];
      a0 += m * wpre[k].x;
      a1 += m * wpre[k].y;
    }
    const float* wp = Wp + pp;
#pragma unroll
    for (int k = 32; k < DIM; ++k) {
      const float2 w2 = *reinterpret_cast<const float2*>(&wp[k * NPROP]);
      const float m = mol_s[k];
      a0 += m * w2.x;
      a1 += m * w2.y;
    }
    *reinterpret_cast<float2*>(&out[(size_t)b * NPROP + pp]) = make_float2(a0, a1);
  }
}

extern "C" void kernel_launch(void* const* d_in, const int* in_sizes, int n_in,
                              void* d_out, int out_size, void* d_ws, size_t ws_size,
                              hipStream_t stream) {
  const int*   fp    = (const int*)d_in[0];
  const float* adj   = (const float*)d_in[1];
  // d_in[2] = mol_size (scalar, hardcoded 64)
  const float* embed = (const float*)d_in[3];
  const float* Wf    = (const float*)d_in[4];
  const float* bfv   = (const float*)d_in[5];
  const float* Wo    = (const float*)d_in[6];
  const float* bo    = (const float*)d_in[7];
  const float* Wp    = (const float*)d_in[8];
  const float* bp    = (const float*)d_in[9];
  float* out = (float*)d_out;
  mgnn_kernel<<<128, 256, 0, stream>>>(fp, adj, embed, Wf, bfv, Wo, bo, Wp, bp, out);
}